// Round 1
// baseline (288.783 us; speedup 1.0000x reference)
//
#include <hip/hip_runtime.h>
#include <hip/hip_bf16.h>
#include <math.h>

// Problem: out = LN2( gelu_erf( LN1(x) @ W^T + bW ) )
// x: [4,4096,2048] f32 -> M=16384 rows, D=2048. W: [2048,2048] f32 (C[m,e]=sum_d h[m,d]*W[e,d]).
// Pipeline: ln1(x)->bf16 ws | W->bf16 ws | MFMA GEMM (NT) + bias+gelu -> f32 d_out | LN2 in-place on d_out.
// ws usage: A_bf16 64MB + W_bf16 8MB = 72MB.

#define D 2048
#define MROWS 16384
#define BM 128
#define BN 128
#define BK 32
#define NT (D / BK)

typedef __bf16 bf16x8 __attribute__((ext_vector_type(8)));
typedef float f32x4 __attribute__((ext_vector_type(4)));

#define GLP(p) ((const __attribute__((address_space(1))) void*)(p))
#define LDSP(p) ((__attribute__((address_space(3))) void*)(p))

__device__ __forceinline__ float gelu_f(float v) {
  return 0.5f * v * (1.0f + erff(v * 0.70710678118654752f));
}

// ---------------- LN1: f32 row -> bf16 row ----------------
__global__ __launch_bounds__(256) void ln1_kernel(
    const float* __restrict__ x, const float* __restrict__ g,
    const float* __restrict__ b, __hip_bfloat16* __restrict__ out) {
  const int tid = threadIdx.x;
  const size_t row = blockIdx.x;
  const float4* xr = (const float4*)(x + row * D);
  float4 v0 = xr[2 * tid];
  float4 v1 = xr[2 * tid + 1];
  float s  = v0.x + v0.y + v0.z + v0.w + v1.x + v1.y + v1.z + v1.w;
  float ss = v0.x*v0.x + v0.y*v0.y + v0.z*v0.z + v0.w*v0.w
           + v1.x*v1.x + v1.y*v1.y + v1.z*v1.z + v1.w*v1.w;
#pragma unroll
  for (int off = 32; off > 0; off >>= 1) {
    s  += __shfl_down(s, off, 64);
    ss += __shfl_down(ss, off, 64);
  }
  __shared__ float red[8];
  const int w = tid >> 6;
  if ((tid & 63) == 0) { red[w] = s; red[w + 4] = ss; }
  __syncthreads();
  s  = red[0] + red[1] + red[2] + red[3];
  ss = red[4] + red[5] + red[6] + red[7];
  const float mu  = s * (1.0f / D);
  const float var = ss * (1.0f / D) - mu * mu;
  const float inv = rsqrtf(var + 1e-5f);
  const float4* gv = (const float4*)g;
  const float4* bv = (const float4*)b;
  float4 g0 = gv[2 * tid], g1 = gv[2 * tid + 1];
  float4 b0 = bv[2 * tid], b1 = bv[2 * tid + 1];
  alignas(16) __hip_bfloat16 h[8];
  h[0] = __float2bfloat16((v0.x - mu) * inv * g0.x + b0.x);
  h[1] = __float2bfloat16((v0.y - mu) * inv * g0.y + b0.y);
  h[2] = __float2bfloat16((v0.z - mu) * inv * g0.z + b0.z);
  h[3] = __float2bfloat16((v0.w - mu) * inv * g0.w + b0.w);
  h[4] = __float2bfloat16((v1.x - mu) * inv * g1.x + b1.x);
  h[5] = __float2bfloat16((v1.y - mu) * inv * g1.y + b1.y);
  h[6] = __float2bfloat16((v1.z - mu) * inv * g1.z + b1.z);
  h[7] = __float2bfloat16((v1.w - mu) * inv * g1.w + b1.w);
  *(uint4*)(out + row * D + (size_t)tid * 8) = *(const uint4*)h;
}

// ---------------- W: f32 -> bf16 ----------------
__global__ __launch_bounds__(256) void cvt_kernel(
    const float* __restrict__ W, __hip_bfloat16* __restrict__ Wb, int n8) {
  const int i = blockIdx.x * 256 + threadIdx.x;
  if (i >= n8) return;
  const float4* p = (const float4*)W + 2 * (size_t)i;
  float4 a = p[0], c = p[1];
  alignas(16) __hip_bfloat16 h[8] = {
      __float2bfloat16(a.x), __float2bfloat16(a.y),
      __float2bfloat16(a.z), __float2bfloat16(a.w),
      __float2bfloat16(c.x), __float2bfloat16(c.y),
      __float2bfloat16(c.z), __float2bfloat16(c.w)};
  *(uint4*)(Wb + (size_t)i * 8) = *(const uint4*)h;
}

// ---------------- GEMM: C = gelu(A @ W^T + bias), A bf16 [M,D], W bf16 [N,D] ----------------
__global__ __launch_bounds__(256) void gemm_kernel(
    const __hip_bfloat16* __restrict__ A,
    const __hip_bfloat16* __restrict__ Bw,
    const float* __restrict__ bias,
    float* __restrict__ C) {
  __shared__ alignas(16) __hip_bfloat16 sA[2][BM * BK];  // 8KB each buf
  __shared__ alignas(16) __hip_bfloat16 sB[2][BN * BK];
  const int tid = threadIdx.x;
  const size_t m0 = (size_t)blockIdx.x * BM;
  const int n0 = blockIdx.y * BN;
  const int l = tid & 63;
  const int w = tid >> 6;
  const int wm = (w >> 1) * 64, wn = (w & 1) * 64;
  const int lr = l & 15, lk = l >> 4;

  f32x4 acc[4][4] = {};

  // staging geometry: linear LDS [row][32] bf16, 64B/row; thread covers two 16B chunks
  const int o0 = tid * 16, o1 = 4096 + tid * 16;
  const int row0 = o0 >> 6, c0 = (o0 >> 4) & 3;
  const int row1 = o1 >> 6, c1 = (o1 >> 4) & 3;
  const __hip_bfloat16* Ag = A + m0 * D;
  const __hip_bfloat16* Bg = Bw + (size_t)n0 * D;

  auto stage = [&](int buf, int kt) {
    const int kb = kt * BK;
    char* la = (char*)&sA[buf][0];
    char* lb = (char*)&sB[buf][0];
    __builtin_amdgcn_global_load_lds(GLP(Ag + (size_t)row0 * D + kb + c0 * 8), LDSP(la + o0), 16, 0, 0);
    __builtin_amdgcn_global_load_lds(GLP(Ag + (size_t)row1 * D + kb + c1 * 8), LDSP(la + o1), 16, 0, 0);
    __builtin_amdgcn_global_load_lds(GLP(Bg + (size_t)row0 * D + kb + c0 * 8), LDSP(lb + o0), 16, 0, 0);
    __builtin_amdgcn_global_load_lds(GLP(Bg + (size_t)row1 * D + kb + c1 * 8), LDSP(lb + o1), 16, 0, 0);
  };

  stage(0, 0);
  int cur = 0;
  for (int kt = 0; kt < NT; ++kt) {
    __syncthreads();                         // stage(kt) drained; prior reads of other buf done
    if (kt + 1 < NT) stage(cur ^ 1, kt + 1); // prefetch next tile into other buffer
    bf16x8 af[4], bf[4];
#pragma unroll
    for (int i = 0; i < 4; ++i) {
      af[i] = *(const bf16x8*)&sA[cur][(wm + i * 16 + lr) * BK + lk * 8];
      bf[i] = *(const bf16x8*)&sB[cur][(wn + i * 16 + lr) * BK + lk * 8];
    }
#pragma unroll
    for (int i = 0; i < 4; ++i)
#pragma unroll
      for (int j = 0; j < 4; ++j)
        acc[i][j] = __builtin_amdgcn_mfma_f32_16x16x32_bf16(af[i], bf[j], acc[i][j], 0, 0, 0);
    cur ^= 1;
  }

  // epilogue: C/D layout col=lane&15, row=(lane>>4)*4+reg (m89/m91-verified)
#pragma unroll
  for (int i = 0; i < 4; ++i) {
    const int r0 = wm + i * 16 + lk * 4;
#pragma unroll
    for (int j = 0; j < 4; ++j) {
      const int col = n0 + wn + j * 16 + lr;
      const float bv = bias[col];
#pragma unroll
      for (int r = 0; r < 4; ++r) {
        float v = acc[i][j][r] + bv;
        C[(m0 + r0 + r) * (size_t)D + col] = gelu_f(v);
      }
    }
  }
}

// ---------------- LN2: in-place f32 ----------------
__global__ __launch_bounds__(256) void ln2_kernel(
    float* __restrict__ C, const float* __restrict__ g, const float* __restrict__ b) {
  const int tid = threadIdx.x;
  const size_t row = blockIdx.x;
  float4* cr = (float4*)(C + row * D);
  float4 v0 = cr[2 * tid], v1 = cr[2 * tid + 1];
  float s  = v0.x + v0.y + v0.z + v0.w + v1.x + v1.y + v1.z + v1.w;
  float ss = v0.x*v0.x + v0.y*v0.y + v0.z*v0.z + v0.w*v0.w
           + v1.x*v1.x + v1.y*v1.y + v1.z*v1.z + v1.w*v1.w;
#pragma unroll
  for (int off = 32; off > 0; off >>= 1) {
    s  += __shfl_down(s, off, 64);
    ss += __shfl_down(ss, off, 64);
  }
  __shared__ float red[8];
  const int w = tid >> 6;
  if ((tid & 63) == 0) { red[w] = s; red[w + 4] = ss; }
  __syncthreads();
  s  = red[0] + red[1] + red[2] + red[3];
  ss = red[4] + red[5] + red[6] + red[7];
  const float mu  = s * (1.0f / D);
  const float var = ss * (1.0f / D) - mu * mu;
  const float inv = rsqrtf(var + 1e-5f);
  const float4* gv = (const float4*)g;
  const float4* bv = (const float4*)b;
  float4 g0 = gv[2 * tid], g1 = gv[2 * tid + 1];
  float4 b0 = bv[2 * tid], b1 = bv[2 * tid + 1];
  float4 o0, o1;
  o0.x = (v0.x - mu) * inv * g0.x + b0.x;
  o0.y = (v0.y - mu) * inv * g0.y + b0.y;
  o0.z = (v0.z - mu) * inv * g0.z + b0.z;
  o0.w = (v0.w - mu) * inv * g0.w + b0.w;
  o1.x = (v1.x - mu) * inv * g1.x + b1.x;
  o1.y = (v1.y - mu) * inv * g1.y + b1.y;
  o1.z = (v1.z - mu) * inv * g1.z + b1.z;
  o1.w = (v1.w - mu) * inv * g1.w + b1.w;
  cr[2 * tid] = o0;
  cr[2 * tid + 1] = o1;
}

extern "C" void kernel_launch(void* const* d_in, const int* in_sizes, int n_in,
                              void* d_out, int out_size, void* d_ws, size_t ws_size,
                              hipStream_t stream) {
  const float* x  = (const float*)d_in[0];
  const float* W  = (const float*)d_in[1];
  const float* bW = (const float*)d_in[2];
  const float* g1 = (const float*)d_in[3];
  const float* b1 = (const float*)d_in[4];
  const float* g2 = (const float*)d_in[5];
  const float* b2 = (const float*)d_in[6];
  float* out = (float*)d_out;

  __hip_bfloat16* Abf = (__hip_bfloat16*)d_ws;                 // 64MB
  __hip_bfloat16* Wbf = Abf + (size_t)MROWS * D;               // +8MB

  ln1_kernel<<<MROWS, 256, 0, stream>>>(x, g1, b1, Abf);
  cvt_kernel<<<(D * D / 8) / 256, 256, 0, stream>>>(W, Wbf, D * D / 8);
  dim3 grid(MROWS / BM, D / BN);
  gemm_kernel<<<grid, 256, 0, stream>>>(Abf, Wbf, bW, out);
  ln2_kernel<<<MROWS, 256, 0, stream>>>(out, g2, b2);
}

// Round 4
// 233.658 us; speedup vs baseline: 1.2359x; 1.2359x over previous
//
#include <hip/hip_runtime.h>
#include <hip/hip_bf16.h>
#include <math.h>

// out = LN2( gelu_erf( LN1(x) @ W^T + bW ) )
// x: [4,4096,2048] f32 -> M=16384 rows. W: [2048,2048] f32, C[m,e]=sum_d h[m,d]*W[e,d].
// GEMM: 256x256 tile, BK=64 split into two K-halves of 32. Phases are K-slices (uniform
// across waves) so counted vmcnt(4)+barrier guarantees exactly the data each phase reads.

#define D 2048
#define MROWS 16384
#define BMT 256
#define BNT 256
#define KTILES (D / 64)  // 32

typedef __bf16 bf16x8 __attribute__((ext_vector_type(8)));
typedef float f32x4 __attribute__((ext_vector_type(4)));

#define GLP(p) ((const __attribute__((address_space(1))) void*)(p))
#define LDSP(p) ((__attribute__((address_space(3))) void*)(p))
#define S_VMCNT(n) asm volatile("s_waitcnt vmcnt(" #n ")" ::: "memory")
#define MEMFENCE() asm volatile("" ::: "memory")
#define BAR() __builtin_amdgcn_s_barrier()
#define SCHED_FENCE() __builtin_amdgcn_sched_barrier(0)

__device__ __forceinline__ float gelu_f(float v) {
  return 0.5f * v * (1.0f + erff(v * 0.70710678118654752f));
}

// ---------------- LN1: f32 row -> bf16 row ----------------
__global__ __launch_bounds__(256) void ln1_kernel(
    const float* __restrict__ x, const float* __restrict__ g,
    const float* __restrict__ b, __hip_bfloat16* __restrict__ out) {
  const int tid = threadIdx.x;
  const size_t row = blockIdx.x;
  const float4* xr = (const float4*)(x + row * D);
  float4 v0 = xr[2 * tid];
  float4 v1 = xr[2 * tid + 1];
  float s  = v0.x + v0.y + v0.z + v0.w + v1.x + v1.y + v1.z + v1.w;
  float ss = v0.x*v0.x + v0.y*v0.y + v0.z*v0.z + v0.w*v0.w
           + v1.x*v1.x + v1.y*v1.y + v1.z*v1.z + v1.w*v1.w;
#pragma unroll
  for (int off = 32; off > 0; off >>= 1) {
    s  += __shfl_down(s, off, 64);
    ss += __shfl_down(ss, off, 64);
  }
  __shared__ float red[8];
  const int w = tid >> 6;
  if ((tid & 63) == 0) { red[w] = s; red[w + 4] = ss; }
  __syncthreads();
  s  = red[0] + red[1] + red[2] + red[3];
  ss = red[4] + red[5] + red[6] + red[7];
  const float mu  = s * (1.0f / D);
  const float var = ss * (1.0f / D) - mu * mu;
  const float inv = rsqrtf(var + 1e-5f);
  const float4* gv = (const float4*)g;
  const float4* bv = (const float4*)b;
  float4 g0 = gv[2 * tid], g1 = gv[2 * tid + 1];
  float4 b0 = bv[2 * tid], b1 = bv[2 * tid + 1];
  alignas(16) __hip_bfloat16 h[8];
  h[0] = __float2bfloat16((v0.x - mu) * inv * g0.x + b0.x);
  h[1] = __float2bfloat16((v0.y - mu) * inv * g0.y + b0.y);
  h[2] = __float2bfloat16((v0.z - mu) * inv * g0.z + b0.z);
  h[3] = __float2bfloat16((v0.w - mu) * inv * g0.w + b0.w);
  h[4] = __float2bfloat16((v1.x - mu) * inv * g1.x + b1.x);
  h[5] = __float2bfloat16((v1.y - mu) * inv * g1.y + b1.y);
  h[6] = __float2bfloat16((v1.z - mu) * inv * g1.z + b1.z);
  h[7] = __float2bfloat16((v1.w - mu) * inv * g1.w + b1.w);
  *(uint4*)(out + row * D + (size_t)tid * 8) = *(const uint4*)h;
}

// ---------------- W: f32 -> bf16 ----------------
__global__ __launch_bounds__(256) void cvt_kernel(
    const float* __restrict__ W, __hip_bfloat16* __restrict__ Wb, int n8) {
  const int i = blockIdx.x * 256 + threadIdx.x;
  if (i >= n8) return;
  const float4* p = (const float4*)W + 2 * (size_t)i;
  float4 a = p[0], c = p[1];
  alignas(16) __hip_bfloat16 h[8] = {
      __float2bfloat16(a.x), __float2bfloat16(a.y),
      __float2bfloat16(a.z), __float2bfloat16(a.w),
      __float2bfloat16(c.x), __float2bfloat16(c.y),
      __float2bfloat16(c.z), __float2bfloat16(c.w)};
  *(uint4*)(Wb + (size_t)i * 8) = *(const uint4*)h;
}

// ---------------- GEMM ----------------
// LDS per operand: [2 buf][2 kh][16KB]; a kh-region holds 256 rows x 32 cols bf16 as
// 128 lines x 128B; (row, chunk lk) at line=row>>1, slot=(2*lk+(row&1))^((row>>1)&7).
// global_load_lds dest is linear (tid*16); the swizzle is applied on the global SOURCE.
__global__ __launch_bounds__(512, 2) void gemm_kernel(
    const __hip_bfloat16* __restrict__ A,
    const __hip_bfloat16* __restrict__ Bw,
    const float* __restrict__ bias,
    float* __restrict__ C) {
  __shared__ __hip_bfloat16 sA[2 * 2 * 256 * 32];  // 64KB
  __shared__ __hip_bfloat16 sB[2 * 2 * 256 * 32];  // 64KB
  const int tid = threadIdx.x;
  const int l = tid & 63;
  const int wid = tid >> 6;
  const int fr = l & 15;
  const int lk = l >> 4;
  const size_t m0 = (size_t)blockIdx.x * BMT;
  const int n0 = blockIdx.y * BNT;
  const int whm = wid >> 2;        // wave's A half (rows whm*128..+127)
  const int wn = (wid & 3) * 64;   // wave's col base in 0..255
  char* const ldsA = (char*)sA;
  char* const ldsB = (char*)sB;

  // ds_read offsets: row_A = whm*128 + mi*16 + fr ; row_B = wn + ni*16 + fr
  // line&7 == fr>>1 for both (bases are multiples of 16); slot per-lane constant:
  const int slot = ((2 * lk + (fr & 1)) ^ (fr >> 1)) << 4;
  const int aoff = whm * 8192 + (fr >> 1) * 128 + slot;
  const int boff = wn * 64 + (fr >> 1) * 128 + slot;

  // staging inverse-swizzle: dest byte tid*16 -> line=tid>>3, s=tid&7;
  // content: v = s ^ (line&7); row = 2*line + (v&1); col = (v>>1)*8.
  const int line = tid >> 3;
  const int v = (tid & 7) ^ (line & 7);
  const int srow0 = 2 * line + (v & 1);
  const int srow1 = srow0 + 128;
  const int scol = (v >> 1) * 8;
  const int ldd0 = tid * 16;
  const int ldd1 = ldd0 + 8192;
  const __hip_bfloat16* const Ag = A + m0 * D;
  const __hip_bfloat16* const Bg = Bw + (size_t)n0 * D;

  auto stg = [&](char* lds, const __hip_bfloat16* G, int so, int kh, int kt) {
    const __hip_bfloat16* s0 = G + (size_t)srow0 * D + kt * 64 + kh * 32 + scol;
    const __hip_bfloat16* s1 = G + (size_t)srow1 * D + kt * 64 + kh * 32 + scol;
    char* q = lds + (so << 15) + (kh << 14);
    __builtin_amdgcn_global_load_lds(GLP(s0), LDSP(q + ldd0), 16, 0, 0);
    __builtin_amdgcn_global_load_lds(GLP(s1), LDSP(q + ldd1), 16, 0, 0);
  };

  bf16x8 a[8], b[4];
  f32x4 acc[8][4] = {};

  auto rd = [&](int bo, int kh) {
    const char* pa = ldsA + bo + (kh << 14) + aoff;
    const char* pb = ldsB + bo + (kh << 14) + boff;
#pragma unroll
    for (int mi = 0; mi < 8; ++mi) a[mi] = *(const bf16x8*)(pa + mi * 1024);
#pragma unroll
    for (int ni = 0; ni < 4; ++ni) b[ni] = *(const bf16x8*)(pb + ni * 1024);
  };
  auto mma = [&]() {
    __builtin_amdgcn_s_setprio(1);
#pragma unroll
    for (int mi = 0; mi < 8; ++mi)
#pragma unroll
      for (int ni = 0; ni < 4; ++ni)
        acc[mi][ni] = __builtin_amdgcn_mfma_f32_16x16x32_bf16(a[mi], b[ni], acc[mi][ni], 0, 0, 0);
    __builtin_amdgcn_s_setprio(0);
  };

  // prologue: tile 0 into buf0; issue order = consumption order: Akh0,Bkh0,Akh1,Bkh1
  stg(ldsA, Ag, 0, 0, 0); stg(ldsB, Bg, 0, 0, 0);
  stg(ldsA, Ag, 0, 1, 0); stg(ldsB, Bg, 0, 1, 0);   // 8 loads in flight

  for (int kt = 0; kt < KTILES - 1; ++kt) {
    const int bo = (kt & 1) << 15;
    const int so = (kt & 1) ^ 1;
    // phase kh=0: retire oldest 4 = this tile's kh0 (A+B); all waves agree after BAR.
    S_VMCNT(4);
    BAR(); MEMFENCE(); SCHED_FENCE();
    rd(bo, 0);
    stg(ldsA, Ag, so, 0, kt + 1); stg(ldsB, Bg, so, 0, kt + 1);  // back to 8
    mma();
    // phase kh=1: retire this tile's kh1.
    S_VMCNT(4);
    BAR(); MEMFENCE(); SCHED_FENCE();
    rd(bo, 1);
    stg(ldsA, Ag, so, 1, kt + 1); stg(ldsB, Bg, so, 1, kt + 1);  // back to 8
    mma();
  }
  // tail tile (no staging)
  {
    const int bo = ((KTILES - 1) & 1) << 15;
    S_VMCNT(4);
    BAR(); MEMFENCE(); SCHED_FENCE();
    rd(bo, 0);
    mma();
    S_VMCNT(0);
    BAR(); MEMFENCE(); SCHED_FENCE();
    rd(bo, 1);
    mma();
  }

  // epilogue: bias + gelu, f32 stores (C/D: col=lane&15, row=(lane>>4)*4+reg)
  float bv[4];
#pragma unroll
  for (int ni = 0; ni < 4; ++ni) bv[ni] = bias[n0 + wn + ni * 16 + fr];
#pragma unroll
  for (int mi = 0; mi < 8; ++mi) {
    const size_t rbase = m0 + whm * 128 + mi * 16 + lk * 4;
#pragma unroll
    for (int rr = 0; rr < 4; ++rr) {
      float* crow = C + (rbase + rr) * D + n0 + wn + fr;
#pragma unroll
      for (int ni = 0; ni < 4; ++ni)
        crow[ni * 16] = gelu_f(acc[mi][ni][rr] + bv[ni]);
    }
  }
}

// ---------------- LN2: in-place f32 ----------------
__global__ __launch_bounds__(256) void ln2_kernel(
    float* __restrict__ C, const float* __restrict__ g, const float* __restrict__ b) {
  const int tid = threadIdx.x;
  const size_t row = blockIdx.x;
  float4* cr = (float4*)(C + row * D);
  float4 v0 = cr[2 * tid], v1 = cr[2 * tid + 1];
  float s  = v0.x + v0.y + v0.z + v0.w + v1.x + v1.y + v1.z + v1.w;
  float ss = v0.x*v0.x + v0.y*v0.y + v0.z*v0.z + v0.w*v0.w
           + v1.x*v1.x + v1.y*v1.y + v1.z*v1.z + v1.w*v1.w;
#pragma unroll
  for (int off = 32; off > 0; off >>= 1) {
    s  += __shfl_down(s, off, 64);
    ss += __shfl_down(ss, off, 64);
  }
  __shared__ float red[8];
  const int w = tid >> 6;
  if ((tid & 63) == 0) { red[w] = s; red[w + 4] = ss; }
  __syncthreads();
  s  = red[0] + red[1] + red[2] + red[3];
  ss = red[4] + red[5] + red[6] + red[7];
  const float mu  = s * (1.0f / D);
  const float var = ss * (1.0f / D) - mu * mu;
  const float inv = rsqrtf(var + 1e-5f);
  const float4* gv = (const float4*)g;
  const float4* bv = (const float4*)b;
  float4 g0 = gv[2 * tid], g1 = gv[2 * tid + 1];
  float4 b0 = bv[2 * tid], b1 = bv[2 * tid + 1];
  float4 o0, o1;
  o0.x = (v0.x - mu) * inv * g0.x + b0.x;
  o0.y = (v0.y - mu) * inv * g0.y + b0.y;
  o0.z = (v0.z - mu) * inv * g0.z + b0.z;
  o0.w = (v0.w - mu) * inv * g0.w + b0.w;
  o1.x = (v1.x - mu) * inv * g1.x + b1.x;
  o1.y = (v1.y - mu) * inv * g1.y + b1.y;
  o1.z = (v1.z - mu) * inv * g1.z + b1.z;
  o1.w = (v1.w - mu) * inv * g1.w + b1.w;
  cr[2 * tid] = o0;
  cr[2 * tid + 1] = o1;
}

extern "C" void kernel_launch(void* const* d_in, const int* in_sizes, int n_in,
                              void* d_out, int out_size, void* d_ws, size_t ws_size,
                              hipStream_t stream) {
  const float* x  = (const float*)d_in[0];
  const float* W  = (const float*)d_in[1];
  const float* bW = (const float*)d_in[2];
  const float* g1 = (const float*)d_in[3];
  const float* b1 = (const float*)d_in[4];
  const float* g2 = (const float*)d_in[5];
  const float* b2 = (const float*)d_in[6];
  float* out = (float*)d_out;

  __hip_bfloat16* Abf = (__hip_bfloat16*)d_ws;            // 64MB
  __hip_bfloat16* Wbf = Abf + (size_t)MROWS * D;          // +8MB

  ln1_kernel<<<MROWS, 256, 0, stream>>>(x, g1, b1, Abf);
  cvt_kernel<<<(D * D / 8) / 256, 256, 0, stream>>>(W, Wbf, D * D / 8);
  dim3 grid(MROWS / BMT, D / BNT);
  gemm_kernel<<<grid, 512, 0, stream>>>(Abf, Wbf, bW, out);
  ln2_kernel<<<MROWS, 256, 0, stream>>>(out, g2, b2);
}